// Round 3
// baseline (142.161 us; speedup 1.0000x reference)
//
#include <hip/hip_runtime.h>

// ContrasPQ forward = per-(b,p) nearest-code lookup.
// s_k = sum_d c_kd * (-2 v_d) + ||c_k||^2  (drops ||v||^2, constant in k).
// R3: codebook is wave-uniform -> read via SCALAR loads (uniform address,
// uniform control flow => compiler emits s_load, broadcast through sK$),
// eliminating the LDS return-bus tax (~40 CU-cyc/code/wave) that bounded
// R1/R2. No LDS at all. Argmin via 8-code chunks + min3 tree + bit-exact
// winning-chunk recompute (identical inlined FMA sequence) for the index.

typedef float f32x2 __attribute__((ext_vector_type(2)));
typedef float f32x4 __attribute__((ext_vector_type(4)));

#define TPB 256   // threads per block
#define KBQ 4     // queries per thread
#define CHUNK 8   // codes per chunk

namespace {
constexpr int kB   = 8192;
constexpr int kEMB = 768;
constexpr int kP   = 96;
constexpr int kK   = 256;
constexpr int kD   = 8;
}

__device__ __forceinline__ f32x2 vfma2(f32x2 a, f32x2 b, f32x2 c) {
    f32x2 d;
    d.x = fmaf(a.x, b.x, c.x);
    d.y = fmaf(a.y, b.y, c.y);
    return d;
}

// ||c||^2 from 4 dim-pairs. Fixed op order (bit-exact between call sites).
__device__ __forceinline__ float code_c2(const f32x2 c[4]) {
    f32x2 t = c[0] * c[0];
    t = vfma2(c[1], c[1], t);
    t = vfma2(c[2], c[2], t);
    t = vfma2(c[3], c[3], t);
    return t.x + t.y;
}

// Score of one code: c . vs + c2, vs = -2*v. Fixed op order; MUST be the
// identical sequence in main loop and epilogue (bit-exact recompute).
__device__ __forceinline__ float code_score(const f32x2 c[4], const f32x2 vs[4],
                                            float c2) {
    f32x2 a = vfma2(c[0], vs[0], f32x2{c2, 0.0f});
    a = vfma2(c[1], vs[1], a);
    a = vfma2(c[2], vs[2], a);
    a = vfma2(c[3], vs[3], a);
    return a.x + a.y;
}

__global__ __launch_bounds__(TPB, 3)
void pq_argmin_kernel(const float* __restrict__ vecs,
                      const float* __restrict__ codebook,
                      float* __restrict__ out)
{
    const int p = blockIdx.y;
    const int t = threadIdx.x;

    // uniform base for this p's codebook slice (8 KB; sK$/L1-hot)
    const float* __restrict__ cbp = codebook + (size_t)p * kK * kD;

    // ---- load KBQ query subvectors, scale by -2 (exact pow2) ----
    const int b0 = blockIdx.x * (TPB * KBQ) + t;
    f32x2 vs[KBQ][4];
#pragma unroll
    for (int q = 0; q < KBQ; ++q) {
        const f32x4* vp = reinterpret_cast<const f32x4*>(
            vecs + (size_t)(b0 + q * TPB) * kEMB + p * kD);
        f32x4 x = vp[0];
        f32x4 y = vp[1];
        vs[q][0] = f32x2{-2.0f * x.x, -2.0f * x.y};
        vs[q][1] = f32x2{-2.0f * x.z, -2.0f * x.w};
        vs[q][2] = f32x2{-2.0f * y.x, -2.0f * y.y};
        vs[q][3] = f32x2{-2.0f * y.z, -2.0f * y.w};
    }

    float best[KBQ];
    int   bch[KBQ];
#pragma unroll
    for (int q = 0; q < KBQ; ++q) {
        best[q] = __builtin_inff();
        bch[q] = 0;
    }

    // ---- main loop: 32 chunks x 8 codes, codebook via scalar loads ----
#pragma unroll 2
    for (int ch = 0; ch < kK / CHUNK; ++ch) {
        // uniform address, uniform control flow -> s_load (wide, merged)
        f32x2 cp[CHUNK][4];
        float c2[CHUNK];
#pragma unroll
        for (int c = 0; c < CHUNK; ++c) {
            const f32x2* cc = reinterpret_cast<const f32x2*>(
                cbp + (ch * CHUNK + c) * kD);
#pragma unroll
            for (int j = 0; j < 4; ++j) cp[c][j] = cc[j];
        }
#pragma unroll
        for (int c = 0; c < CHUNK; ++c) c2[c] = code_c2(cp[c]);

#pragma unroll
        for (int q = 0; q < KBQ; ++q) {
            float s0 = code_score(cp[0], vs[q], c2[0]);
            float s1 = code_score(cp[1], vs[q], c2[1]);
            float s2 = code_score(cp[2], vs[q], c2[2]);
            float s3 = code_score(cp[3], vs[q], c2[3]);
            float s4 = code_score(cp[4], vs[q], c2[4]);
            float s5 = code_score(cp[5], vs[q], c2[5]);
            float s6 = code_score(cp[6], vs[q], c2[6]);
            float s7 = code_score(cp[7], vs[q], c2[7]);
            // min3 tree: 8 -> 1 in 4 ops (min of distinct finites returns
            // an operand exactly -> bit-exact recompute works)
            float m1 = fminf(fminf(s0, s1), s2);   // v_min3
            float m2 = fminf(fminf(s3, s4), s5);   // v_min3
            float m3 = fminf(fminf(s6, s7), m1);   // v_min3
            float m  = fminf(m2, m3);
            if (m < best[q]) {   // strict <: earlier chunk wins ties
                best[q] = m;
                bch[q] = ch;
            }
        }
    }

    // ---- epilogue: recompute winning chunk (bit-exact, same values from
    //      the same memory), first-index match, emit codebook row ----
#pragma unroll
    for (int q = 0; q < KBQ; ++q) {
        const int base = bch[q] * CHUNK;
        float s[CHUNK];
#pragma unroll
        for (int c = 0; c < CHUNK; ++c) {
            f32x2 cc[4];
            const f32x2* src = reinterpret_cast<const f32x2*>(
                cbp + (base + c) * kD);
#pragma unroll
            for (int j = 0; j < 4; ++j) cc[j] = src[j];
            s[c] = code_score(cc, vs[q], code_c2(cc));
        }
        int idx = base;
        bool fnd = (s[0] == best[q]);
#pragma unroll
        for (int c = 1; c < CHUNK; ++c) {
            bool e = (s[c] == best[q]) && !fnd;
            idx = e ? base + c : idx;
            fnd = fnd || (s[c] == best[q]);
        }
        const f32x4* row = reinterpret_cast<const f32x4*>(cbp + idx * kD);
        f32x4 r0 = row[0];
        f32x4 r1 = row[1];
        f32x4* op = reinterpret_cast<f32x4*>(
            out + (size_t)(b0 + q * TPB) * kEMB + p * kD);
        op[0] = r0;
        op[1] = r1;
    }
}

extern "C" void kernel_launch(void* const* d_in, const int* in_sizes, int n_in,
                              void* d_out, int out_size, void* d_ws, size_t ws_size,
                              hipStream_t stream)
{
    const float* vecs     = (const float*)d_in[0];
    const float* codebook = (const float*)d_in[1];
    float* out            = (float*)d_out;

    dim3 grid(kB / (TPB * KBQ), kP, 1);  // (8, 96) = 768 blocks = 3/CU
    dim3 block(TPB, 1, 1);
    hipLaunchKernelGGL(pq_argmin_kernel, grid, block, 0, stream,
                       vecs, codebook, out);
}